// Round 1
// baseline (7638.920 us; speedup 1.0000x reference)
//
#include <hip/hip_runtime.h>
#include <hip/hip_bf16.h>

typedef __attribute__((ext_vector_type(8))) short short8v;
typedef __attribute__((ext_vector_type(4))) float f32x4;
typedef __attribute__((ext_vector_type(4))) float float4v;

#define DEV __device__ __forceinline__

DEV short f2bfs(float x){
  union { float f; unsigned u; } v; v.f = x;
  unsigned r = (v.u + 0x7FFFu + ((v.u >> 16) & 1u)) >> 16;
  return (short)(unsigned short)r;
}
DEV float bfs2f(short s){
  union { unsigned u; float f; } v; v.u = ((unsigned)(unsigned short)s) << 16;
  return v.f;
}
DEV float sigm(float x){ return 1.f / (1.f + __expf(-x)); }
// glu-pair interleave map: z-col j (0..2047) -> row n' so a-col and gate-col land
// 16 apart inside one wave's 32-col strip (same lane holds both).
DEV int zmap(int j){ int g = (j >= 1024) ? 1 : 0; int i = j - (g << 10); return (i & 15) + ((i >> 4) << 5) + (g << 4); }

// ---------------- generic thin-M MFMA GEMM: C[M,N] = A[M,K] * B(N,K)^T ----------------
// block: 256 thr = 4 waves; block tile M=64 x N=128; wave: 4 m-frags x 2 n-frags.
struct EpiF32 {
  float* C; int ldc;
  DEV void op(const f32x4 (&acc)[4][2], int m0, int n0, int l15, int l4, const float* bias) const {
#pragma unroll
    for (int mi = 0; mi < 4; mi++)
#pragma unroll
      for (int ni = 0; ni < 2; ni++){
        int n = n0 + ni*16 + l15;
        float bb = bias ? bias[n] : 0.f;
#pragma unroll
        for (int r = 0; r < 4; r++){
          int m = m0 + mi*16 + l4*4 + r;
          C[(size_t)m*ldc + n] = acc[mi][ni][r] + bb;
        }
      }
  }
};

struct EpiBF16 {
  short* C; int ldc; int domap;
  DEV void op(const f32x4 (&acc)[4][2], int m0, int n0, int l15, int l4, const float* bias) const {
#pragma unroll
    for (int mi = 0; mi < 4; mi++)
#pragma unroll
      for (int ni = 0; ni < 2; ni++){
        int n = n0 + ni*16 + l15;
        float bb = bias ? bias[n] : 0.f;
#pragma unroll
        for (int r = 0; r < 4; r++){
          int m = m0 + mi*16 + l4*4 + r;
          int mr = domap ? zmap(m) : m;
          C[(size_t)mr*ldc + n] = f2bfs(acc[mi][ni][r] + bb);
        }
      }
  }
};

struct EpiQKV { // K5: n<1024 -> Qbuf slot, <2048 -> Kbuf slot, else vcur f32
  short* Qb; short* Kb; float* vc; int slot;
  DEV void op(const f32x4 (&acc)[4][2], int m0, int n0, int l15, int l4, const float* bias) const {
#pragma unroll
    for (int mi = 0; mi < 4; mi++)
#pragma unroll
      for (int ni = 0; ni < 2; ni++){
        int n = n0 + ni*16 + l15;
#pragma unroll
        for (int r = 0; r < 4; r++){
          int m = m0 + mi*16 + l4*4 + r;
          float v = acc[mi][ni][r];
          if (n < 1024)       Qb[((size_t)m*1024 + n)*32 + slot] = f2bfs(v);
          else if (n < 2048)  Kb[((size_t)m*1024 + (n-1024))*32 + slot] = f2bfs(v);
          else                vc[(size_t)m*1024 + (n-2048)] = v;
        }
      }
  }
};

struct EpiPred { // E1: m = b*50+t ; out[b][n][t]
  float* outp;
  DEV void op(const f32x4 (&acc)[4][2], int m0, int n0, int l15, int l4, const float* bias) const {
#pragma unroll
    for (int mi = 0; mi < 4; mi++)
#pragma unroll
      for (int ni = 0; ni < 2; ni++){
        int n = n0 + ni*16 + l15;
        if (n >= 1000) continue;
        float bb = bias[n];
#pragma unroll
        for (int r = 0; r < 4; r++){
          int m = m0 + mi*16 + l4*4 + r;
          int b = m / 50, tt = m - b*50;
          outp[(size_t)b*50000 + (size_t)n*50 + tt] = acc[mi][ni][r] + bb;
        }
      }
  }
};

struct EpiGlu { // K3: u[i]=a*sig(g), partial LN stats via atomics
  float* u; float* stats;
  DEV void op(const f32x4 (&acc)[4][2], int m0, int n0, int l15, int l4, const float* bias) const {
    float ba = bias[n0 + l15], bg = bias[n0 + 16 + l15];
    int i = l15 + ((n0 >> 5) << 4);
#pragma unroll
    for (int mi = 0; mi < 4; mi++)
#pragma unroll
      for (int r = 0; r < 4; r++){
        int m = m0 + mi*16 + l4*4 + r;
        float a = acc[mi][0][r] + ba;
        float g = acc[mi][1][r] + bg;
        float uv = a * sigm(g);
        u[(size_t)m*1024 + i] = uv;
        float s = uv, s2 = uv*uv;
#pragma unroll
        for (int off = 1; off < 16; off <<= 1){ s += __shfl_xor(s, off); s2 += __shfl_xor(s2, off); }
        if (l15 == 0){ atomicAdd(&stats[m], s); atomicAdd(&stats[64 + m], s2); }
      }
  }
};

struct EpiKVpre { // P2: bf16 store + per-row LN stats
  short* C; float* stats;
  DEV void op(const f32x4 (&acc)[4][2], int m0, int n0, int l15, int l4, const float* bias) const {
    float b0 = bias[n0 + l15], b1 = bias[n0 + 16 + l15];
#pragma unroll
    for (int mi = 0; mi < 4; mi++)
#pragma unroll
      for (int r = 0; r < 4; r++){
        int m = m0 + mi*16 + l4*4 + r;
        float v0 = acc[mi][0][r] + b0;
        float v1 = acc[mi][1][r] + b1;
        C[(size_t)m*512 + n0 + l15]      = f2bfs(v0);
        C[(size_t)m*512 + n0 + 16 + l15] = f2bfs(v1);
        float s = v0 + v1, s2 = v0*v0 + v1*v1;
#pragma unroll
        for (int off = 1; off < 16; off <<= 1){ s += __shfl_xor(s, off); s2 += __shfl_xor(s2, off); }
        if (l15 == 0){ atomicAdd(&stats[m*2], s); atomicAdd(&stats[m*2 + 1], s2); }
      }
  }
};

template<bool ABF16, typename EPI>
__global__ __launch_bounds__(256) void gemm_tn(const void* __restrict__ Aptr, int lda,
    const short* __restrict__ Bw, int ldb, const float* __restrict__ bias,
    int K, float* zbuf, int zn, EPI epi)
{
  int tid = threadIdx.x;
  if (zbuf != nullptr && blockIdx.x == 0 && blockIdx.y == 0 && tid < zn) zbuf[tid] = 0.f;
  const int w = tid >> 6, l15 = tid & 15, l4 = (tid >> 4) & 3;
  const int m0 = blockIdx.y * 64;
  const int n0 = blockIdx.x * 128 + w * 32;
  f32x4 acc[4][2];
#pragma unroll
  for (int mi = 0; mi < 4; mi++)
#pragma unroll
    for (int ni = 0; ni < 2; ni++)
      acc[mi][ni] = (f32x4){0.f, 0.f, 0.f, 0.f};
#pragma unroll 4
  for (int kk = 0; kk < K; kk += 32){
    const int ks = kk + l4*8;
    short8v a[4], bfr[2];
#pragma unroll
    for (int mi = 0; mi < 4; mi++){
      const size_t row = (size_t)(m0 + mi*16 + l15);
      if (ABF16){
        a[mi] = *(const short8v*)((const short*)Aptr + row*lda + ks);
      } else {
        const float* ap = (const float*)Aptr + row*lda + ks;
        float4v f0 = *(const float4v*)ap;
        float4v f1 = *(const float4v*)(ap + 4);
        short8v t;
        t[0]=f2bfs(f0[0]); t[1]=f2bfs(f0[1]); t[2]=f2bfs(f0[2]); t[3]=f2bfs(f0[3]);
        t[4]=f2bfs(f1[0]); t[5]=f2bfs(f1[1]); t[6]=f2bfs(f1[2]); t[7]=f2bfs(f1[3]);
        a[mi] = t;
      }
    }
#pragma unroll
    for (int ni = 0; ni < 2; ni++)
      bfr[ni] = *(const short8v*)(Bw + (size_t)(n0 + ni*16 + l15)*ldb + ks);
#pragma unroll
    for (int mi = 0; mi < 4; mi++)
#pragma unroll
      for (int ni = 0; ni < 2; ni++)
        acc[mi][ni] = __builtin_amdgcn_mfma_f32_16x16x32_bf16(a[mi], bfr[ni], acc[mi][ni], 0, 0, 0);
  }
  epi.op(acc, m0, n0, l15, l4, bias);
}

// ---------------- cross-attention (per (h,b) block) ----------------
__global__ __launch_bounds__(256) void cross_attn_k(const float* __restrict__ Qh,
    const short* __restrict__ Kc, const short* __restrict__ Vc, short* __restrict__ oa_bf)
{
  int h = blockIdx.x, b = blockIdx.y, tid = threadIdx.x;
  __shared__ float qs[64];
  __shared__ float wsm[256];
  __shared__ float red[256];
  if (tid < 64) qs[tid] = Qh[b*512 + h*64 + tid];
  __syncthreads();
  float sv = -1e30f;
  if (tid < 196){
    const short* kp = Kc + ((size_t)(b*196 + tid)*512 + h*64);
    float acc = 0.f;
#pragma unroll
    for (int j = 0; j < 64; j += 8){
      short8v kv8 = *(const short8v*)(kp + j);
#pragma unroll
      for (int u8 = 0; u8 < 8; u8++) acc += bfs2f(kv8[u8]) * qs[j + u8];
    }
    sv = acc * 0.125f;
  }
  red[tid] = sv; __syncthreads();
  for (int s = 128; s > 0; s >>= 1){ if (tid < s) red[tid] = fmaxf(red[tid], red[tid + s]); __syncthreads(); }
  float M = red[0]; __syncthreads();
  float e = (tid < 196) ? __expf(sv - M) : 0.f;
  wsm[tid] = e; red[tid] = e; __syncthreads();
  for (int s = 128; s > 0; s >>= 1){ if (tid < s) red[tid] += red[tid + s]; __syncthreads(); }
  float Z = red[0]; __syncthreads();
  int d = tid & 63, c = tid >> 6;
  float acc = 0.f;
  for (int s = c; s < 196; s += 4) acc += wsm[s] * bfs2f(Vc[(size_t)(b*196 + s)*512 + h*64 + d]);
  red[tid] = acc; __syncthreads();
  if (tid < 64){
    float o = (red[tid] + red[tid + 64] + red[tid + 128] + red[tid + 192]) / Z;
    oa_bf[(size_t)b*1536 + h*64 + tid] = f2bfs(o);
  }
}

// ---------------- LN + trace append + per-neuron NLM ----------------
__global__ __launch_bounds__(256) void nlm_k(const float* __restrict__ u, const float* __restrict__ stats,
    const float* __restrict__ g_s, const float* __restrict__ g_b,
    float* __restrict__ st, const float* __restrict__ w1, const float* __restrict__ b1,
    const float* __restrict__ w2, const float* __restrict__ b2, short* __restrict__ oa_bf, int t)
{
  int tid = threadIdx.x;
  int d_i = tid & 15, b_i = (tid >> 4) & 7, half = tid >> 7;
  int d = blockIdx.x*16 + d_i, b = blockIdx.y*8 + b_i;
  float mu = stats[b] * (1.f/1024.f);
  float var = stats[64 + b] * (1.f/1024.f) - mu*mu;
  float rs = rsqrtf(var + 1e-5f);
  float uv = u[b*1024 + d];
  float state = (uv - mu)*rs*g_s[d] + g_b[d];
  int slot = t % 25;
  if (half == 0) st[((size_t)b*1024 + d)*25 + slot] = state;
  // window in logical order m=0..24 (p = (t+1+m) mod 25); newest == state (in-register)
  float stv[25];
  int p0 = (t + 1) % 25;
#pragma unroll
  for (int m = 0; m < 25; m++){
    int p = p0 + m; if (p >= 25) p -= 25;
    stv[m] = (p == slot) ? state : st[((size_t)b*1024 + d)*25 + p];
  }
  float pre[16];
#pragma unroll
  for (int hh = 0; hh < 16; hh++) pre[hh] = b1[d*32 + half*16 + hh];
  for (int m = 0; m < 25; m++){
    float sm = stv[m];
#pragma unroll
    for (int hh = 0; hh < 16; hh++) pre[hh] += sm * w1[(size_t)(m*32 + half*16 + hh)*1024 + d];
  }
  __shared__ float pl[2][8][16][16];
#pragma unroll
  for (int hh = 0; hh < 16; hh++) pl[half][b_i][hh][d_i] = pre[hh];
  __syncthreads();
  if (half == 0){
    float p2a = b2[d*2 + 0], p2g = b2[d*2 + 1];
#pragma unroll
    for (int i = 0; i < 16; i++){
      float hv = pl[0][b_i][i][d_i] * sigm(pl[1][b_i][i][d_i]);
      p2a += hv * w2[(size_t)(i*2 + 0)*1024 + d];
      p2g += hv * w2[(size_t)(i*2 + 1)*1024 + d];
    }
    float act = p2a * sigm(p2g);
    oa_bf[(size_t)b*1536 + 512 + d] = f2bfs(act);
  }
}

// ---------------- neuron-sync attention (per (h,b) block, MFMA scores) ----------------
__global__ __launch_bounds__(256) void sync_attn_k(const short* __restrict__ Qbuf, const short* __restrict__ Kbuf,
    const float* __restrict__ vcur, float* __restrict__ S, short* __restrict__ S_bf,
    short* __restrict__ SyncO, int t)
{
  int h = blockIdx.x, b = blockIdx.y, tid = threadIdx.x;
  __shared__ short8v qlds[512];
  __shared__ short8v klds[512];
  const short* qg = Qbuf + ((size_t)b*1024 + h*128)*32;
  const short* kg = Kbuf + ((size_t)b*1024 + h*128)*32;
#pragma unroll
  for (int it = 0; it < 2; it++){
    int ch = tid + 256*it;           // 512 chunks of 16B per operand
    int d = ch >> 2, c = ch & 3;
    int cs = c ^ ((d >> 1) & 3);     // bank-spread swizzle
    qlds[d*4 + cs] = *(const short8v*)(qg + d*32 + c*8);
    klds[d*4 + cs] = *(const short8v*)(kg + d*32 + c*8);
  }
  __syncthreads();
  int w = tid >> 6, l15 = tid & 15, l4 = (tid >> 4) & 3;
  short8v af[2], bfr[8];
#pragma unroll
  for (int mi2 = 0; mi2 < 2; mi2++){
    int d = (2*w + mi2)*16 + l15;
    af[mi2] = qlds[d*4 + (l4 ^ ((d >> 1) & 3))];
  }
#pragma unroll
  for (int ni = 0; ni < 8; ni++){
    int e = ni*16 + l15;
    bfr[ni] = klds[e*4 + (l4 ^ ((e >> 1) & 3))];
  }
  f32x4 acc[2][8];
#pragma unroll
  for (int mi2 = 0; mi2 < 2; mi2++)
#pragma unroll
    for (int ni = 0; ni < 8; ni++)
      acc[mi2][ni] = (f32x4){0.f,0.f,0.f,0.f};
#pragma unroll
  for (int mi2 = 0; mi2 < 2; mi2++)
#pragma unroll
    for (int ni = 0; ni < 8; ni++)
      acc[mi2][ni] = __builtin_amdgcn_mfma_f32_16x16x32_bf16(af[mi2], bfr[ni], acc[mi2][ni], 0, 0, 0);
  float Vv[8];
#pragma unroll
  for (int ni = 0; ni < 8; ni++) Vv[ni] = vcur[b*1024 + h*128 + ni*16 + l15];
  const float scale = 0.08838834764831845f; // 1/sqrt(128)
#pragma unroll
  for (int mi2 = 0; mi2 < 2; mi2++)
#pragma unroll
    for (int r = 0; r < 4; r++){
      float sv[8]; float mx = -1e30f;
#pragma unroll
      for (int ni = 0; ni < 8; ni++){ sv[ni] = acc[mi2][ni][r]*scale; mx = fmaxf(mx, sv[ni]); }
#pragma unroll
      for (int off = 1; off < 16; off <<= 1) mx = fmaxf(mx, __shfl_xor(mx, off));
      float den = 0.f, num = 0.f;
#pragma unroll
      for (int ni = 0; ni < 8; ni++){ float p = __expf(sv[ni] - mx); den += p; num += p*Vv[ni]; }
#pragma unroll
      for (int off = 1; off < 16; off <<= 1){ den += __shfl_xor(den, off); num += __shfl_xor(num, off); }
      if (l15 == 0){
        int d = (2*w + mi2)*16 + l4*4 + r;
        float att = num / den;
        int oi = b*1024 + d*8 + h;
        S[oi] = att;
        S_bf[oi] = f2bfs(att);
        if (t >= 0) SyncO[((size_t)b*50 + t)*1024 + d*8 + h] = f2bfs(att);
      }
    }
}

// ---------------- small utility kernels ----------------
__global__ __launch_bounds__(256) void vecmat_k(const float* __restrict__ W, int ldw,
    const float* __restrict__ v, const float* __restrict__ add, float* __restrict__ out, int K, int domap)
{
  int w = threadIdx.x >> 6, l = threadIdx.x & 63;
  int n = blockIdx.x*4 + w;
  float s = 0.f;
  for (int k = l; k < K; k += 64) s += W[(size_t)n*ldw + k]*v[k];
#pragma unroll
  for (int off = 32; off; off >>= 1) s += __shfl_xor(s, off);
  if (l == 0){ float o = s + (add ? add[n] : 0.f); out[domap ? zmap(n) : n] = o; }
}

__global__ void castW_k(short* dst, int dld, int drow0, int dcol0,
    const float* src, int sld, int N, int K, int transp, int domap)
{
  size_t idx = (size_t)blockIdx.x*256 + threadIdx.x;
  size_t tot = (size_t)N*K;
  if (idx >= tot) return;
  int n = idx / K, k = idx - (size_t)n*K;
  float vv = 0.f;
  if (src) vv = transp ? src[(size_t)k*sld + n] : src[(size_t)n*sld + k];
  int r = drow0 + (domap ? zmap(n) : n);
  dst[(size_t)r*dld + dcol0 + k] = f2bfs(vv);
}

__global__ void zero_k(float* p, int n){
  int i = blockIdx.x*256 + threadIdx.x;
  if (i < n) p[i] = 0.f;
}

__global__ void ln_inplace_k(short* kvp, const float* __restrict__ stats,
    const float* __restrict__ s, const float* __restrict__ bb)
{
  size_t i = (size_t)blockIdx.x*256 + threadIdx.x;
  int row = i >> 9, c = i & 511;
  float mu = stats[row*2] * (1.f/512.f);
  float var = stats[row*2 + 1] * (1.f/512.f) - mu*mu;
  float v = bfs2f(kvp[i]);
  kvp[i] = f2bfs((v - mu)*rsqrtf(var + 1e-5f)*s[c] + bb[c]);
}

__global__ void fill_k(short* Qbuf, short* Kbuf, float* vcur, short* oa_bf,
    float* st, const float* q0, const float* k0, const float* v0,
    const float* start, const float* strace)
{
  size_t i = (size_t)blockIdx.x*256 + threadIdx.x;
  const size_t R0 = 64u*1024u*32u;
  if (i < R0){
    int c = i & 31; int d = (i >> 5) & 1023;
    Qbuf[i] = (c < 25) ? f2bfs(q0[d]) : 0;
    Kbuf[i] = (c < 25) ? f2bfs(k0[d]) : 0;
    return;
  }
  i -= R0;
  if (i < 65536){
    int d = i & 1023; int b = i >> 10;
    vcur[i] = v0[d];
    oa_bf[(size_t)b*1536 + 512 + d] = f2bfs(start[d]);
    return;
  }
  i -= 65536;
  if (i < (size_t)64*1024*25){
    st[i] = strace[i % 25600];
  }
}

__global__ __launch_bounds__(256) void cert_k(const float* __restrict__ preds, float* __restrict__ cert)
{
  int t = blockIdx.x, b = blockIdx.y, tid = threadIdx.x;
  __shared__ float red[256];
  float v[4]; float mx = -1e30f;
#pragma unroll
  for (int i = 0; i < 4; i++){
    int o = tid + i*256;
    v[i] = (o < 1000) ? preds[(size_t)b*50000 + (size_t)o*50 + t] : -1e30f;
    mx = fmaxf(mx, v[i]);
  }
  red[tid] = mx; __syncthreads();
  for (int s = 128; s; s >>= 1){ if (tid < s) red[tid] = fmaxf(red[tid], red[tid + s]); __syncthreads(); }
  float M = red[0]; __syncthreads();
  float z = 0.f, wsum = 0.f;
#pragma unroll
  for (int i = 0; i < 4; i++){
    int o = tid + i*256;
    if (o < 1000){ float p = v[i] - M; float e = __expf(p); z += e; wsum += e*p; }
  }
  red[tid] = z; __syncthreads();
  for (int s = 128; s; s >>= 1){ if (tid < s) red[tid] += red[tid + s]; __syncthreads(); }
  float Z = red[0]; __syncthreads();
  red[tid] = wsum; __syncthreads();
  for (int s = 128; s; s >>= 1){ if (tid < s) red[tid] += red[tid + s]; __syncthreads(); }
  float Wm = red[0];
  if (tid == 0){
    float ne = (__logf(Z) - Wm/Z) * 0.14476482730108392f; // 1/ln(1000)
    cert[b*100 + t] = ne;
    cert[b*100 + 50 + t] = 1.f - ne;
  }
}

__global__ void copy_sync_k(const float* __restrict__ S, float* __restrict__ out){
  int i = blockIdx.x*256 + threadIdx.x;
  out[i] = S[i];
}

// ============================== host ==============================
extern "C" void kernel_launch(void* const* d_in, const int* in_sizes, int n_in,
                              void* d_out, int out_size, void* d_ws, size_t ws_size,
                              hipStream_t stream)
{
  const float* x        = (const float*)d_in[0];
  const float* kv_w     = (const float*)d_in[1];
  const float* kv_b     = (const float*)d_in[2];
  const float* ln_kv_s  = (const float*)d_in[3];
  const float* ln_kv_b  = (const float*)d_in[4];
  const float* q_w      = (const float*)d_in[5];
  const float* q_b      = (const float*)d_in[6];
  const float* in_proj_w= (const float*)d_in[7];
  const float* in_proj_b= (const float*)d_in[8];
  const float* out_proj_w=(const float*)d_in[9];
  const float* out_proj_b=(const float*)d_in[10];
  const float* W_q      = (const float*)d_in[11];
  const float* W_k      = (const float*)d_in[12];
  const float* W_v      = (const float*)d_in[13];
  const float* syn_w    = (const float*)d_in[14];
  const float* syn_b    = (const float*)d_in[15];
  const float* syn_ln_s = (const float*)d_in[16];
  const float* syn_ln_b = (const float*)d_in[17];
  const float* nlm_w1   = (const float*)d_in[18];
  const float* nlm_b1   = (const float*)d_in[19];
  const float* nlm_w2   = (const float*)d_in[20];
  const float* nlm_b2   = (const float*)d_in[21];
  const float* start_act= (const float*)d_in[22];
  const float* strace   = (const float*)d_in[23];
  const float* out_w    = (const float*)d_in[24];
  const float* out_b    = (const float*)d_in[25];
  float* out = (float*)d_out;

  char* ws = (char*)d_ws;
  size_t off = 0;
  auto alloc = [&](size_t bytes)->char*{ char* p = ws + off; off = (off + bytes + 255) & ~(size_t)255; return p; };

  short* qw_B   = (short*)alloc((size_t)1024*512*2);
  short* opw_B  = (short*)alloc((size_t)512*512*2);
  short* Wfq    = (short*)alloc((size_t)512*1024*2);
  float* bfq    = (float*)alloc(512*4);
  short* Wz     = (short*)alloc((size_t)2048*1536*2);
  float* bz     = (float*)alloc(2048*4);
  short* Wqkv   = (short*)alloc((size_t)3072*1024*2);
  short* outwB  = (short*)alloc((size_t)1024*1024*2);
  short* kvw_B  = (short*)alloc((size_t)512*512*2);
  short* wkc_B  = (short*)alloc((size_t)512*512*2);
  short* wvc_B  = (short*)alloc((size_t)512*512*2);
  short* kvp    = (short*)alloc((size_t)12544*512*2);
  float* kvstats= (float*)alloc((size_t)25088*4);
  short* Kc     = (short*)alloc((size_t)12544*512*2);
  short* Vc     = (short*)alloc((size_t)12544*512*2);
  short* Qbuf   = (short*)alloc((size_t)64*1024*32*2);
  short* Kbuf   = (short*)alloc((size_t)64*1024*32*2);
  float* vcur   = (float*)alloc((size_t)65536*4);
  float* S      = (float*)alloc((size_t)65536*4);
  short* S_bf   = (short*)alloc((size_t)65536*2);
  short* SyncO  = (short*)alloc((size_t)64*50*1024*2);
  float* Qh     = (float*)alloc((size_t)32768*4);
  short* oa_bf  = (short*)alloc((size_t)64*1536*2);
  float* ubuf   = (float*)alloc((size_t)65536*4);
  float* stats  = (float*)alloc(128*4);
  float* st     = (float*)alloc((size_t)1638400*4);
  float* q0     = (float*)alloc(1024*4);
  float* k0     = (float*)alloc(1024*4);
  float* v0     = (float*)alloc(1024*4);
  (void)ws_size; (void)in_sizes; (void)n_in; (void)out_size;

  dim3 blk(256);

  // ---- prologue: weight prep ----
  castW_k<<<dim3((1024*512+255)/256), blk, 0, stream>>>(qw_B, 512, 0, 0, q_w, 1024, 1024, 512, 1, 0);
  castW_k<<<dim3((512*512+255)/256), blk, 0, stream>>>(opw_B, 512, 0, 0, out_proj_w, 512, 512, 512, 1, 0);
  castW_k<<<dim3((2048*1024+255)/256), blk, 0, stream>>>(Wz, 1536, 0, 512, syn_w + 512, 1536, 2048, 1024, 0, 1);
  castW_k<<<dim3((1024*1024+255)/256), blk, 0, stream>>>(Wqkv, 1024, 0, 0, W_q, 1024, 1024, 1024, 0, 0);
  castW_k<<<dim3((1024*1024+255)/256), blk, 0, stream>>>(Wqkv, 1024, 1024, 0, W_k, 1024, 1024, 1024, 0, 0);
  castW_k<<<dim3((1024*1024+255)/256), blk, 0, stream>>>(Wqkv, 1024, 2048, 0, W_v, 1024, 1024, 1024, 0, 0);
  castW_k<<<dim3((1000*1024+255)/256), blk, 0, stream>>>(outwB, 1024, 0, 0, out_w, 1024, 1000, 1024, 0, 0);
  castW_k<<<dim3((24*1024+255)/256), blk, 0, stream>>>(outwB, 1024, 1000, 0, nullptr, 0, 24, 1024, 0, 0);
  castW_k<<<dim3((512*512+255)/256), blk, 0, stream>>>(kvw_B, 512, 0, 0, kv_w, 512, 512, 512, 0, 0);
  castW_k<<<dim3((512*512+255)/256), blk, 0, stream>>>(wkc_B, 512, 0, 0, in_proj_w + 512*512, 512, 512, 512, 0, 0);
  castW_k<<<dim3((512*512+255)/256), blk, 0, stream>>>(wvc_B, 512, 0, 0, in_proj_w + 1024*512, 512, 512, 512, 0, 0);

  vecmat_k<<<dim3(256), blk, 0, stream>>>(W_q, 1024, start_act, nullptr, q0, 1024, 0);
  vecmat_k<<<dim3(256), blk, 0, stream>>>(W_k, 1024, start_act, nullptr, k0, 1024, 0);
  vecmat_k<<<dim3(256), blk, 0, stream>>>(W_v, 1024, start_act, nullptr, v0, 1024, 0);
  vecmat_k<<<dim3(128), blk, 0, stream>>>(in_proj_w, 512, q_b, in_proj_b, bfq, 512, 0);
  vecmat_k<<<dim3(512), blk, 0, stream>>>(syn_w, 1536, out_proj_b, syn_b, bz, 512, 1);

  gemm_tn<false, EpiBF16><<<dim3(8, 8), blk, 0, stream>>>(in_proj_w, 512, qw_B, 512, nullptr, 512, nullptr, 0, EpiBF16{Wfq, 1024, 0});
  gemm_tn<false, EpiBF16><<<dim3(4, 32), blk, 0, stream>>>(syn_w, 1536, opw_B, 512, nullptr, 512, nullptr, 0, EpiBF16{Wz, 1536, 1});

  zero_k<<<dim3(98), blk, 0, stream>>>(kvstats, 25088);
  gemm_tn<false, EpiKVpre><<<dim3(4, 196), blk, 0, stream>>>(x, 512, kvw_B, 512, kv_b, 512, nullptr, 0, EpiKVpre{kvp, kvstats});
  ln_inplace_k<<<dim3(25088), blk, 0, stream>>>(kvp, kvstats, ln_kv_s, ln_kv_b);
  gemm_tn<true, EpiBF16><<<dim3(4, 196), blk, 0, stream>>>(kvp, 512, wkc_B, 512, in_proj_b + 512, 512, nullptr, 0, EpiBF16{Kc, 512, 0});
  gemm_tn<true, EpiBF16><<<dim3(4, 196), blk, 0, stream>>>(kvp, 512, wvc_B, 512, in_proj_b + 1024, 512, nullptr, 0, EpiBF16{Vc, 512, 0});

  fill_k<<<dim3(14848), blk, 0, stream>>>(Qbuf, Kbuf, vcur, oa_bf, st, q0, k0, v0, start_act, strace);
  sync_attn_k<<<dim3(8, 64), blk, 0, stream>>>(Qbuf, Kbuf, vcur, S, S_bf, SyncO, -1); // sync_a(0)

  // ---- 50 thought ticks ----
  for (int t = 0; t < 50; t++){
    gemm_tn<true, EpiF32><<<dim3(4, 1), blk, 0, stream>>>(S_bf, 1024, Wfq, 1024, bfq, 1024, stats, 128, EpiF32{Qh, 512});
    cross_attn_k<<<dim3(8, 64), blk, 0, stream>>>(Qh, Kc, Vc, oa_bf);
    gemm_tn<true, EpiGlu><<<dim3(16, 1), blk, 0, stream>>>(oa_bf, 1536, Wz, 1536, bz, 1536, nullptr, 0, EpiGlu{ubuf, stats});
    nlm_k<<<dim3(64, 8), blk, 0, stream>>>(ubuf, stats, syn_ln_s, syn_ln_b, st, nlm_w1, nlm_b1, nlm_w2, nlm_b2, oa_bf, t);
    gemm_tn<true, EpiQKV><<<dim3(24, 1), blk, 0, stream>>>(oa_bf + 512, 1536, Wqkv, 1024, nullptr, 1024, nullptr, 0, EpiQKV{Qbuf, Kbuf, vcur, t % 25});
    sync_attn_k<<<dim3(8, 64), blk, 0, stream>>>(Qbuf, Kbuf, vcur, S, S_bf, SyncO, t);
  }

  // ---- epilogue: deferred output head ----
  gemm_tn<true, EpiPred><<<dim3(8, 50), blk, 0, stream>>>(SyncO, 1024, outwB, 1024, out_b, 1024, nullptr, 0, EpiPred{out});
  cert_k<<<dim3(50, 64), blk, 0, stream>>>(out, out + 3200000);
  copy_sync_k<<<dim3(256), blk, 0, stream>>>(S, out + 3206400);
}